// Round 1
// baseline (303.894 us; speedup 1.0000x reference)
//
#include <hip/hip_runtime.h>

// IMM loss: G=8192 groups of M=16 particles, D=64 dims each, fp32.
// terms = Lap(x,x) + Lap(y,y) - 2*Lap(x,y), Lap = exp(-ws[j]*max(||a-b||,EPS)/D).
//
// R3: Gram-form distances + chunked software pipeline.
//  - ||a-b||^2 = ||a||^2 + ||b||^2 - 2 a.b: per-dim work drops from
//    {2 ROT + 3 sub + 3 fma} to {2 ROT + 3 fma} per FULL offset; rotated
//    norms cost ONE DPP per offset at the end (was per-dim subtraction).
//  - D processed in 4 chunks of 16 dims with next-chunk prefetch into a
//    second register buffer: HBM latency (~900 cyc) hides under ~1800 cyc
//    of per-chunk VALU, fixing the load->compute serialization that the
//    structural 2-waves/SIMD occupancy (2048 waves total) cannot hide.
//  - Rolled chunk loop keeps code ~8 KB (I-cache resident; R2 was ~48 KB).

#define EPS_D 0.006f
#define DIMS 64
#define CH   16
#define NCH  (DIMS / CH)

// Rotate within each 16-lane row by O (O = 1..15, compile-time constant).
#define ROT(v, O) __int_as_float(__builtin_amdgcn_update_dpp(              \
        0, __float_as_int(v), 0x120 + (O), 0xF, 0xF, false))

__global__ __launch_bounds__(256, 2)
void imm_loss_kernel(const float* __restrict__ ys_t,
                     const float* __restrict__ ys_r,
                     const float* __restrict__ w_scale,
                     const float* __restrict__ time_w,
                     float* __restrict__ partials)
{
    const int tid  = threadIdx.x;
    const int lane = tid & 63;
    const int wave = tid >> 6;
    const int b    = (blockIdx.x * 4 + wave) * 64 + lane;  // global row = g*16 + j

    // Scalars early so their latency is hidden under the main loop.
    const float s_j = w_scale[b] * (1.0f / (float)DIMS);   // ws[j]/D
    const float tw  = time_w[b & ~15];                     // time_weights[g*16]

    const float4* xp = reinterpret_cast<const float4*>(ys_t + (size_t)b * DIMS);
    const float4* yp = reinterpret_cast<const float4*>(ys_r + (size_t)b * DIMS);

    // Accumulators: norms + cross-dot Gram terms per offset class.
    float nx = 0.f, ny = 0.f, g0 = 0.f;
    float gxx[8], gyy[8], gxy[8], hxy[7];
    #pragma unroll
    for (int i = 0; i < 8; ++i) { gxx[i] = 0.f; gyy[i] = 0.f; gxy[i] = 0.f; }
    #pragma unroll
    for (int i = 0; i < 7; ++i) hxy[i] = 0.f;

    // Double-buffered chunk registers.
    float xc[CH], yc[CH], xn[CH], yn[CH];

    // Prologue: chunk 0 -> current buffer.
    #pragma unroll
    for (int q = 0; q < CH / 4; ++q) {
        float4 v = xp[q];
        xc[4*q+0] = v.x; xc[4*q+1] = v.y; xc[4*q+2] = v.z; xc[4*q+3] = v.w;
        float4 w = yp[q];
        yc[4*q+0] = w.x; yc[4*q+1] = w.y; yc[4*q+2] = w.z; yc[4*q+3] = w.w;
    }

    #pragma unroll 1
    for (int c = 0; c < NCH; ++c) {
        // Issue next chunk's loads before computing the current chunk.
        if (c + 1 < NCH) {
            #pragma unroll
            for (int q = 0; q < CH / 4; ++q) {
                float4 v = xp[(c + 1) * (CH / 4) + q];
                xn[4*q+0] = v.x; xn[4*q+1] = v.y; xn[4*q+2] = v.z; xn[4*q+3] = v.w;
                float4 w = yp[(c + 1) * (CH / 4) + q];
                yn[4*q+0] = w.x; yn[4*q+1] = w.y; yn[4*q+2] = w.z; yn[4*q+3] = w.w;
            }
        }

        // Accumulate norms + cross-dots for this chunk.
        #pragma unroll
        for (int d = 0; d < CH; ++d) {
            const float xd = xc[d], yd = yc[d];
            nx = fmaf(xd, xd, nx);
            ny = fmaf(yd, yd, ny);
            g0 = fmaf(xd, yd, g0);

#define ACC_FULL(O) {                                                      \
            const float xr = ROT(xd, O);                                   \
            const float yr = ROT(yd, O);                                   \
            gxx[(O)-1] = fmaf(xr, xd, gxx[(O)-1]);                         \
            gyy[(O)-1] = fmaf(yr, yd, gyy[(O)-1]);                         \
            gxy[(O)-1] = fmaf(yr, xd, gxy[(O)-1]); }
#define ACC_XY(O) {                                                        \
            const float yr = ROT(yd, O);                                   \
            hxy[(O)-9] = fmaf(yr, xd, hxy[(O)-9]); }

            ACC_FULL(1) ACC_FULL(2) ACC_FULL(3) ACC_FULL(4)
            ACC_FULL(5) ACC_FULL(6) ACC_FULL(7) ACC_FULL(8)
            ACC_XY(9)  ACC_XY(10) ACC_XY(11) ACC_XY(12)
            ACC_XY(13) ACC_XY(14) ACC_XY(15)
        }

        // Swap buffers (compiler waits vmcnt here, after compute -> overlap).
        if (c + 1 < NCH) {
            #pragma unroll
            for (int q = 0; q < CH; ++q) { xc[q] = xn[q]; yc[q] = yn[q]; }
        }
    }

    // ---- Finalize: distances from Gram terms, then exps. ----
    // xx and yy diagonals: d=0 clamps to EPS.
    float acc = 2.0f * __expf(-s_j * EPS_D);

    // offset 0: xy pair (j, j).
    {
        const float d2 = fmaxf(nx + ny - 2.0f * g0, 0.0f);
        const float dd = fmaxf(sqrtf(d2), EPS_D);
        acc -= 2.0f * __expf(-s_j * dd);
    }

    // Offsets 1..8: xx & yy via symmetry (offset 8 double-covered -> 0.5),
    // plus the xy term (always full weight -2: xy matrix is asymmetric, each
    // ordered difference class appears exactly once across offsets 0..15).
#define FIN_FULL(O, W) {                                                   \
        const float sk  = ROT(s_j, O);                                     \
        const float nxr = ROT(nx, O);                                      \
        const float nyr = ROT(ny, O);                                      \
        const float ddx = fmaxf(sqrtf(fmaxf(nx + nxr - 2.0f*gxx[(O)-1], 0.f)), EPS_D); \
        const float ddy = fmaxf(sqrtf(fmaxf(ny + nyr - 2.0f*gyy[(O)-1], 0.f)), EPS_D); \
        const float ddz = fmaxf(sqrtf(fmaxf(nx + nyr - 2.0f*gxy[(O)-1], 0.f)), EPS_D); \
        acc += (W) * (__expf(-s_j * ddx) + __expf(-sk * ddx));             \
        acc += (W) * (__expf(-s_j * ddy) + __expf(-sk * ddy));             \
        acc -= 2.0f * __expf(-s_j * ddz); }

#define FIN_XY(O) {                                                        \
        const float nyr = ROT(ny, O);                                      \
        const float ddz = fmaxf(sqrtf(fmaxf(nx + nyr - 2.0f*hxy[(O)-9], 0.f)), EPS_D); \
        acc -= 2.0f * __expf(-s_j * ddz); }

    FIN_FULL(1, 1.0f)
    FIN_FULL(2, 1.0f)
    FIN_FULL(3, 1.0f)
    FIN_FULL(4, 1.0f)
    FIN_FULL(5, 1.0f)
    FIN_FULL(6, 1.0f)
    FIN_FULL(7, 1.0f)
    FIN_FULL(8, 0.5f)
    FIN_XY(9)
    FIN_XY(10)
    FIN_XY(11)
    FIN_XY(12)
    FIN_XY(13)
    FIN_XY(14)
    FIN_XY(15)

    // tw is uniform per 16-lane cluster; wave reduction sums 4 groups.
    float val = acc * tw;
    #pragma unroll
    for (int off = 32; off; off >>= 1)
        val += __shfl_xor(val, off, 64);

    __shared__ float smem[4];
    if (lane == 0) smem[wave] = val;
    __syncthreads();
    if (tid == 0)
        partials[blockIdx.x] = smem[0] + smem[1] + smem[2] + smem[3];
}

__global__ void imm_reduce_kernel(const float* __restrict__ part, int n,
                                  float inv_scale, float* __restrict__ out)
{
    const int tid = threadIdx.x;
    float v = 0.f;
    for (int i = tid; i < n; i += 256) v += part[i];
    #pragma unroll
    for (int off = 32; off; off >>= 1) v += __shfl_xor(v, off, 64);
    __shared__ float s[4];
    if ((tid & 63) == 0) s[tid >> 6] = v;
    __syncthreads();
    if (tid == 0) out[0] = (s[0] + s[1] + s[2] + s[3]) * inv_scale;
}

extern "C" void kernel_launch(void* const* d_in, const int* in_sizes, int n_in,
                              void* d_out, int out_size, void* d_ws, size_t ws_size,
                              hipStream_t stream)
{
    const float* ys_t = (const float*)d_in[0];
    const float* ys_r = (const float*)d_in[1];
    const float* wsc  = (const float*)d_in[2];
    const float* twp  = (const float*)d_in[3];
    float* out      = (float*)d_out;
    float* partials = (float*)d_ws;

    const int B = in_sizes[2];      // 131072 (w_scale element count)
    const int G = B / 16;           // 8192 groups
    const int blocks = G / 16;      // 16 groups per block (4 waves x 4 groups)

    imm_loss_kernel<<<blocks, 256, 0, stream>>>(ys_t, ys_r, wsc, twp, partials);

    const float inv_scale = 1.0f / (256.0f * (float)G);  // 1/(M*M*G)
    imm_reduce_kernel<<<1, 256, 0, stream>>>(partials, blocks, inv_scale, out);
}

// Round 3
// 145.088 us; speedup vs baseline: 2.0946x; 2.0946x over previous
//
#include <hip/hip_runtime.h>

// IMM loss: G=8192 groups of M=16 particles, D=64 dims each, fp32.
// terms = Lap(x,x) + Lap(y,y) - 2*Lap(x,y), Lap = exp(-ws[j]*max(||a-b||,EPS)/D).
//
// R5 == R4 resubmitted verbatim (R4's bench was an infra failure: "MI355X
// container failed twice" — kernel never ran; no evidence against it).
//
// R4: Gram-form distances (R3's algebra, verified absmax=0) on R2's
// fully-unrolled structure (R2's codegen, verified no spill).
// R3 post-mortem: the rolled chunk loop + conditional register-array swap
// defeated SROA -> xc/yc/xn/yn demoted to scratch -> 880 MB of HBM traffic
// (FETCH 324 MB + WRITE 534 MB for a 67 MB-input kernel), 229 us.
// Fix: every array access is a compile-time constant index again. Two named
// 16-dim chunk buffers in a hand-unrolled load/compute ping-pong give one
// chunk of prefetch depth (load latency hides under ~1.8k cyc of VALU) with
// ~110 VGPRs total (64 chunk + 26 Gram accumulators), no spill possible.

#define EPS_D 0.006f
#define DIMS 64

// Rotate within each 16-lane row by O (O = 1..15, compile-time constant).
#define ROT(v, O) __int_as_float(__builtin_amdgcn_update_dpp(              \
        0, __float_as_int(v), 0x120 + (O), 0xF, 0xF, false))

__global__ __launch_bounds__(256, 2)
void imm_loss_kernel(const float* __restrict__ ys_t,
                     const float* __restrict__ ys_r,
                     const float* __restrict__ w_scale,
                     const float* __restrict__ time_w,
                     float* __restrict__ partials)
{
    const int tid  = threadIdx.x;
    const int lane = tid & 63;
    const int wave = tid >> 6;
    const int b    = (blockIdx.x * 4 + wave) * 64 + lane;  // global row = g*16 + j

    // Scalars early so their latency hides under the main pipeline.
    const float s_j = w_scale[b] * (1.0f / (float)DIMS);   // ws[j]/D
    const float tw  = time_w[b & ~15];                     // time_weights[g*16]

    const float4* xp = reinterpret_cast<const float4*>(ys_t + (size_t)b * DIMS);
    const float4* yp = reinterpret_cast<const float4*>(ys_r + (size_t)b * DIMS);

    // Gram accumulators: norms + cross-dots per offset class.
    float nx = 0.f, ny = 0.f, g0 = 0.f;
    float gxx[8], gyy[8], gxy[8], hxy[7];
    #pragma unroll
    for (int i = 0; i < 8; ++i) { gxx[i] = 0.f; gyy[i] = 0.f; gxy[i] = 0.f; }
    #pragma unroll
    for (int i = 0; i < 7; ++i) hxy[i] = 0.f;

    // Two named chunk buffers; all accesses constant-indexed (SROA-safe).
    float xa[16], ya[16], xb[16], yb[16];

#define LOADC(C, X, Y) {                                                   \
        _Pragma("unroll")                                                  \
        for (int q = 0; q < 4; ++q) {                                      \
            float4 v = xp[(C) * 4 + q];                                    \
            X[4*q+0] = v.x; X[4*q+1] = v.y; X[4*q+2] = v.z; X[4*q+3] = v.w;\
            float4 w = yp[(C) * 4 + q];                                    \
            Y[4*q+0] = w.x; Y[4*q+1] = w.y; Y[4*q+2] = w.z; Y[4*q+3] = w.w;\
        } }

#define ACC_FULL(O) {                                                      \
            const float xr = ROT(xd, O);                                   \
            const float yr = ROT(yd, O);                                   \
            gxx[(O)-1] = fmaf(xr, xd, gxx[(O)-1]);                         \
            gyy[(O)-1] = fmaf(yr, yd, gyy[(O)-1]);                         \
            gxy[(O)-1] = fmaf(yr, xd, gxy[(O)-1]); }
#define ACC_XY(O) {                                                        \
            const float yr = ROT(yd, O);                                   \
            hxy[(O)-9] = fmaf(yr, xd, hxy[(O)-9]); }

#define COMPC(X, Y) {                                                      \
        _Pragma("unroll")                                                  \
        for (int d = 0; d < 16; ++d) {                                     \
            const float xd = X[d], yd = Y[d];                              \
            nx = fmaf(xd, xd, nx);                                         \
            ny = fmaf(yd, yd, ny);                                         \
            g0 = fmaf(xd, yd, g0);                                         \
            ACC_FULL(1) ACC_FULL(2) ACC_FULL(3) ACC_FULL(4)                \
            ACC_FULL(5) ACC_FULL(6) ACC_FULL(7) ACC_FULL(8)                \
            ACC_XY(9)  ACC_XY(10) ACC_XY(11) ACC_XY(12)                    \
            ACC_XY(13) ACC_XY(14) ACC_XY(15)                               \
        } }

    // Hand-unrolled ping-pong: one chunk of prefetch depth, no rolled loop.
    LOADC(0, xa, ya)
    LOADC(1, xb, yb)
    COMPC(xa, ya)
    LOADC(2, xa, ya)
    COMPC(xb, yb)
    LOADC(3, xb, yb)
    COMPC(xa, ya)
    COMPC(xb, yb)

    // ---- Finalize: distances from Gram terms, then exps. ----
    // xx and yy diagonals: d=0 clamps to EPS.
    float acc = 2.0f * __expf(-s_j * EPS_D);

    // offset 0: xy pair (j, j).
    {
        const float d2 = fmaxf(nx + ny - 2.0f * g0, 0.0f);
        const float dd = fmaxf(sqrtf(d2), EPS_D);
        acc -= 2.0f * __expf(-s_j * dd);
    }

    // Offsets 1..8: xx & yy via symmetry (offset 8 double-covered -> 0.5),
    // plus the xy term (always full weight -2: each ordered xy pair class
    // appears exactly once across offsets 0..15).
#define FIN_FULL(O, W) {                                                   \
        const float sk  = ROT(s_j, O);                                     \
        const float nxr = ROT(nx, O);                                      \
        const float nyr = ROT(ny, O);                                      \
        const float ddx = fmaxf(sqrtf(fmaxf(nx + nxr - 2.0f*gxx[(O)-1], 0.f)), EPS_D); \
        const float ddy = fmaxf(sqrtf(fmaxf(ny + nyr - 2.0f*gyy[(O)-1], 0.f)), EPS_D); \
        const float ddz = fmaxf(sqrtf(fmaxf(nx + nyr - 2.0f*gxy[(O)-1], 0.f)), EPS_D); \
        acc += (W) * (__expf(-s_j * ddx) + __expf(-sk * ddx));             \
        acc += (W) * (__expf(-s_j * ddy) + __expf(-sk * ddy));             \
        acc -= 2.0f * __expf(-s_j * ddz); }

#define FIN_XY(O) {                                                        \
        const float nyr = ROT(ny, O);                                      \
        const float ddz = fmaxf(sqrtf(fmaxf(nx + nyr - 2.0f*hxy[(O)-9], 0.f)), EPS_D); \
        acc -= 2.0f * __expf(-s_j * ddz); }

    FIN_FULL(1, 1.0f)
    FIN_FULL(2, 1.0f)
    FIN_FULL(3, 1.0f)
    FIN_FULL(4, 1.0f)
    FIN_FULL(5, 1.0f)
    FIN_FULL(6, 1.0f)
    FIN_FULL(7, 1.0f)
    FIN_FULL(8, 0.5f)
    FIN_XY(9)
    FIN_XY(10)
    FIN_XY(11)
    FIN_XY(12)
    FIN_XY(13)
    FIN_XY(14)
    FIN_XY(15)

    // tw is uniform per 16-lane cluster; wave reduction sums 4 groups.
    float val = acc * tw;
    #pragma unroll
    for (int off = 32; off; off >>= 1)
        val += __shfl_xor(val, off, 64);

    __shared__ float smem[4];
    if (lane == 0) smem[wave] = val;
    __syncthreads();
    if (tid == 0)
        partials[blockIdx.x] = smem[0] + smem[1] + smem[2] + smem[3];
}

__global__ void imm_reduce_kernel(const float* __restrict__ part, int n,
                                  float inv_scale, float* __restrict__ out)
{
    const int tid = threadIdx.x;
    float v = 0.f;
    for (int i = tid; i < n; i += 256) v += part[i];
    #pragma unroll
    for (int off = 32; off; off >>= 1) v += __shfl_xor(v, off, 64);
    __shared__ float s[4];
    if ((tid & 63) == 0) s[tid >> 6] = v;
    __syncthreads();
    if (tid == 0) out[0] = (s[0] + s[1] + s[2] + s[3]) * inv_scale;
}

extern "C" void kernel_launch(void* const* d_in, const int* in_sizes, int n_in,
                              void* d_out, int out_size, void* d_ws, size_t ws_size,
                              hipStream_t stream)
{
    const float* ys_t = (const float*)d_in[0];
    const float* ys_r = (const float*)d_in[1];
    const float* wsc  = (const float*)d_in[2];
    const float* twp  = (const float*)d_in[3];
    float* out      = (float*)d_out;
    float* partials = (float*)d_ws;

    const int B = in_sizes[2];      // 131072 (w_scale element count)
    const int G = B / 16;           // 8192 groups
    const int blocks = G / 16;      // 16 groups per block (4 waves x 4 groups)

    imm_loss_kernel<<<blocks, 256, 0, stream>>>(ys_t, ys_r, wsc, twp, partials);

    const float inv_scale = 1.0f / (256.0f * (float)G);  // 1/(M*M*G)
    imm_reduce_kernel<<<1, 256, 0, stream>>>(partials, blocks, inv_scale, out);
}

// Round 4
// 122.285 us; speedup vs baseline: 2.4851x; 1.1865x over previous
//
#include <hip/hip_runtime.h>

// IMM loss: G=8192 groups of M=16 particles, D=64 dims each, fp32.
// terms = Lap(x,x) + Lap(y,y) - 2*Lap(x,y), Lap = exp(-ws[j]*max(||a-b||,EPS)/D).
//
// R6: one GROUP per wave — 64 lanes = 16 particles (j, low 4 bits, so DPP
// row_ror still rotates particles) x 4 dim-quarters (db). Fixes R5's two
// counter-diagnosed diseases:
//  - FETCH was 3x input (202 MB): per-lane 256B-strided row reads fragment
//    128B lines across time-separated chunks -> evict+refetch. Now each
//    wave's group block is CONTIGUOUS 4KB (x) + 4KB (y), staged with
//    perfectly-coalesced float4 loads and ds_write_b128 (wave-local, no
//    barriers), XOR-swizzled (granule ^ (row&7)) so the per-lane
//    ds_read_b128 readback is bank-conflict-free (8 lanes/slot-position).
//  - VGPR=36 showed the compiler collapsed the ping-pong -> zero prefetch
//    depth at 2 waves/SIMD. Now grid is 4x (8192 waves, ~5 waves/SIMD,
//    LDS 32KB/block) and latency hides under TLP, no software pipeline.
// Gram accumulators are per-16-dim partials, reduced over db via
// shfl_xor(16/32); finalization is R5's verified-verbatim code. Final
// 64-lane butterfly yields 4x the group sum -> host inv_scale /4.

#define EPS_D 0.006f

// Rotate within each 16-lane row by O (O = 1..15, compile-time constant).
#define ROT(v, O) __int_as_float(__builtin_amdgcn_update_dpp(              \
        0, __float_as_int(v), 0x120 + (O), 0xF, 0xF, false))

__global__ __launch_bounds__(256, 4)
void imm_loss_kernel(const float* __restrict__ ys_t,
                     const float* __restrict__ ys_r,
                     const float* __restrict__ w_scale,
                     const float* __restrict__ time_w,
                     float* __restrict__ partials)
{
    const int tid  = threadIdx.x;
    const int lane = tid & 63;
    const int wave = tid >> 6;
    const int g    = blockIdx.x * 4 + wave;   // one group per wave
    const int j    = lane & 15;               // particle index (DPP axis)
    const int db   = lane >> 4;               // dim-quarter 0..3

    // Per-wave LDS: x granules [0,256), y granules [256,512). 16B granules.
    __shared__ float4 lds4[4][512];           // 32 KB / block

    // ---- Stage: contiguous 4KB x-block + 4KB y-block -> LDS, XOR-swizzled.
    // Slot (r,q) receives global granule (r, q^(r&7)); writes are contiguous
    // (slot = k*64+lane) -> conflict-free; source stays within the same
    // 128B lines (XOR permutes granules only inside 8-granule blocks).
    const float4* xg = reinterpret_cast<const float4*>(ys_t + (size_t)g * 1024);
    const float4* yg = reinterpret_cast<const float4*>(ys_r + (size_t)g * 1024);

    float4 xs[4], yv[4];
    #pragma unroll
    for (int k = 0; k < 4; ++k) {
        const int r  = 4 * k + db;            // row this lane stages
        const int gq = j ^ (r & 7);           // swizzled source granule
        xs[k] = xg[r * 16 + gq];
        yv[k] = yg[r * 16 + gq];
    }
    #pragma unroll
    for (int k = 0; k < 4; ++k) {
        lds4[wave][k * 64 + lane]       = xs[k];
        lds4[wave][256 + k * 64 + lane] = yv[k];
    }

    const float s_j = w_scale[g * 16 + j] * (1.0f / 64.0f);  // ws[j]/D
    const float tw  = time_w[g * 16];                        // uniform per wave

    // ---- Read back this lane's 16 dims (row j, granules db*4..db*4+3).
    // Global granule (j,gq) lives at slot (j, gq^(j&7)); slot positions
    // span all 8 -> conflict-free ds_read_b128.
    float xarr[16], yarr[16];
    #pragma unroll
    for (int m = 0; m < 4; ++m) {
        const int sl = (db * 4 + m) ^ (j & 7);
        const float4 xv = lds4[wave][j * 16 + sl];
        const float4 yw = lds4[wave][256 + j * 16 + sl];
        xarr[4*m+0] = xv.x; xarr[4*m+1] = xv.y; xarr[4*m+2] = xv.z; xarr[4*m+3] = xv.w;
        yarr[4*m+0] = yw.x; yarr[4*m+1] = yw.y; yarr[4*m+2] = yw.z; yarr[4*m+3] = yw.w;
    }

    // ---- Gram accumulation over this lane's 16 dims.
    float nx = 0.f, ny = 0.f, g0 = 0.f;
    float gxx[8], gyy[8], gxy[8], hxy[7];
    #pragma unroll
    for (int i = 0; i < 8; ++i) { gxx[i] = 0.f; gyy[i] = 0.f; gxy[i] = 0.f; }
    #pragma unroll
    for (int i = 0; i < 7; ++i) hxy[i] = 0.f;

#define ACC_FULL(O) {                                                      \
            const float xr = ROT(xd, O);                                   \
            const float yr = ROT(yd, O);                                   \
            gxx[(O)-1] = fmaf(xr, xd, gxx[(O)-1]);                         \
            gyy[(O)-1] = fmaf(yr, yd, gyy[(O)-1]);                         \
            gxy[(O)-1] = fmaf(yr, xd, gxy[(O)-1]); }
#define ACC_XY(O) {                                                        \
            const float yr = ROT(yd, O);                                   \
            hxy[(O)-9] = fmaf(yr, xd, hxy[(O)-9]); }

    #pragma unroll
    for (int d = 0; d < 16; ++d) {
        const float xd = xarr[d], yd = yarr[d];
        nx = fmaf(xd, xd, nx);
        ny = fmaf(yd, yd, ny);
        g0 = fmaf(xd, yd, g0);
        ACC_FULL(1) ACC_FULL(2) ACC_FULL(3) ACC_FULL(4)
        ACC_FULL(5) ACC_FULL(6) ACC_FULL(7) ACC_FULL(8)
        ACC_XY(9)  ACC_XY(10) ACC_XY(11) ACC_XY(12)
        ACC_XY(13) ACC_XY(14) ACC_XY(15)
    }

    // ---- Reduce partial Gram terms over the 4 dim-quarters (db axis).
#define RED(v) { v += __shfl_xor(v, 16, 64); v += __shfl_xor(v, 32, 64); }
    RED(nx) RED(ny) RED(g0)
    #pragma unroll
    for (int i = 0; i < 8; ++i) { RED(gxx[i]) RED(gyy[i]) RED(gxy[i]) }
    #pragma unroll
    for (int i = 0; i < 7; ++i) { RED(hxy[i]) }

    // ---- Finalize (verbatim from R5, absmax=0 verified): distances from
    // Gram terms, then exps. All db rows compute identical values.
    float acc = 2.0f * __expf(-s_j * EPS_D);

    {
        const float d2 = fmaxf(nx + ny - 2.0f * g0, 0.0f);
        const float dd = fmaxf(sqrtf(d2), EPS_D);
        acc -= 2.0f * __expf(-s_j * dd);
    }

#define FIN_FULL(O, W) {                                                   \
        const float sk  = ROT(s_j, O);                                     \
        const float nxr = ROT(nx, O);                                      \
        const float nyr = ROT(ny, O);                                      \
        const float ddx = fmaxf(sqrtf(fmaxf(nx + nxr - 2.0f*gxx[(O)-1], 0.f)), EPS_D); \
        const float ddy = fmaxf(sqrtf(fmaxf(ny + nyr - 2.0f*gyy[(O)-1], 0.f)), EPS_D); \
        const float ddz = fmaxf(sqrtf(fmaxf(nx + nyr - 2.0f*gxy[(O)-1], 0.f)), EPS_D); \
        acc += (W) * (__expf(-s_j * ddx) + __expf(-sk * ddx));             \
        acc += (W) * (__expf(-s_j * ddy) + __expf(-sk * ddy));             \
        acc -= 2.0f * __expf(-s_j * ddz); }

#define FIN_XY(O) {                                                        \
        const float nyr = ROT(ny, O);                                      \
        const float ddz = fmaxf(sqrtf(fmaxf(nx + nyr - 2.0f*hxy[(O)-9], 0.f)), EPS_D); \
        acc -= 2.0f * __expf(-s_j * ddz); }

    FIN_FULL(1, 1.0f)
    FIN_FULL(2, 1.0f)
    FIN_FULL(3, 1.0f)
    FIN_FULL(4, 1.0f)
    FIN_FULL(5, 1.0f)
    FIN_FULL(6, 1.0f)
    FIN_FULL(7, 1.0f)
    FIN_FULL(8, 0.5f)
    FIN_XY(9)
    FIN_XY(10)
    FIN_XY(11)
    FIN_XY(12)
    FIN_XY(13)
    FIN_XY(14)
    FIN_XY(15)

    // ---- 64-lane butterfly: sums 16 particles x 4 identical db copies
    // = 4x group sum (folded into host inv_scale).
    float val = acc * tw;
    #pragma unroll
    for (int off = 32; off; off >>= 1)
        val += __shfl_xor(val, off, 64);

    __shared__ float smem[4];
    if (lane == 0) smem[wave] = val;
    __syncthreads();
    if (tid == 0)
        partials[blockIdx.x] = smem[0] + smem[1] + smem[2] + smem[3];
}

__global__ void imm_reduce_kernel(const float* __restrict__ part, int n,
                                  float inv_scale, float* __restrict__ out)
{
    const int tid = threadIdx.x;
    float v = 0.f;
    for (int i = tid; i < n; i += 256) v += part[i];
    #pragma unroll
    for (int off = 32; off; off >>= 1) v += __shfl_xor(v, off, 64);
    __shared__ float s[4];
    if ((tid & 63) == 0) s[tid >> 6] = v;
    __syncthreads();
    if (tid == 0) out[0] = (s[0] + s[1] + s[2] + s[3]) * inv_scale;
}

extern "C" void kernel_launch(void* const* d_in, const int* in_sizes, int n_in,
                              void* d_out, int out_size, void* d_ws, size_t ws_size,
                              hipStream_t stream)
{
    const float* ys_t = (const float*)d_in[0];
    const float* ys_r = (const float*)d_in[1];
    const float* wsc  = (const float*)d_in[2];
    const float* twp  = (const float*)d_in[3];
    float* out      = (float*)d_out;
    float* partials = (float*)d_ws;

    const int B = in_sizes[2];      // 131072 (w_scale element count)
    const int G = B / 16;           // 8192 groups
    const int blocks = G / 4;       // one group per wave, 4 waves per block

    imm_loss_kernel<<<blocks, 256, 0, stream>>>(ys_t, ys_r, wsc, twp, partials);

    // Sum of partials = 4 * sum_g(tw_g * terms_g); divide by M*M*G and the 4.
    const float inv_scale = 1.0f / (1024.0f * (float)G);
    imm_reduce_kernel<<<1, 256, 0, stream>>>(partials, blocks, inv_scale, out);
}